// Round 4
// baseline (567.194 us; speedup 1.0000x reference)
//
#include <hip/hip_runtime.h>

// PiecewiseContEmbeddings: B=4096, N=64, K=128, E=512, fp32.
//
// Identity: boundaries rows are sorted, so the reference's mask is
//   mask[b,n,k] = 1 (k < bidx), frac (k == bidx), 0 (k > bidx).
// Hence out[b,n,:] = relu( lerp(C[n,bidx,:], C[n,bidx+1,:], frac) )
// with C[n,j,:] = bias[n,:] + prefix_sum_{k<j} weight[n,k,:].
// O(B*N*K*E) einsum -> O(B*N*E) 2-row gather + lerp.
//
// Budget (measured): harness poison fill ~345us (untouchable) + ours ~209us.
// Controllable floor ~100us (512MiB out-write @ 6.3TB/s = 85us + C traffic).
// R2->R3 isolated change: gather stores nt -> regular cached f32x4 stores
// (m13's 6.29TB/s ceiling was measured with cached stores; nt bypasses L2
// write-combining and the L2-pollution concern is moot: hot C slab = 258KB).
// R3 bench was an infra failure (container died); resubmitting unchanged.

#define BB 4096
#define NN 64
#define KK 128
#define EE 512
#define EPSF 1e-8f

typedef float f32x4 __attribute__((ext_vector_type(4)));

// ---- Kernel 1: C[n,j,e] = bias[n,e] + sum_{k<j} weight[n,k,e], j in [0,K]
// Block-scan: 512 blocks x 256 thr. Block = (n, 64-wide e-chunk).
// tid = seg*64 + ec; seg in [0,4) owns k-range [seg*32, seg*32+32).
__global__ __launch_bounds__(256) void cumsum_kernel(
        const float* __restrict__ weight,
        const float* __restrict__ bias,
        float* __restrict__ C) {
    int n   = blockIdx.x >> 3;          // 64 n values
    int e0  = (blockIdx.x & 7) << 6;    // 8 chunks of 64 e
    int ec  = threadIdx.x & 63;
    int seg = threadIdx.x >> 6;         // wave id == segment id (uniform/wave)
    int e   = e0 + ec;

    const float* w = weight + ((size_t)(n * KK + seg * 32)) * EE + e;
    float r[32];
    float run = 0.f;
#pragma unroll
    for (int kk = 0; kk < 32; ++kk) {
        run += __builtin_nontemporal_load(&w[(size_t)kk * EE]);  // weight read once
        r[kk] = run;
    }

    __shared__ float part[4][64];
    part[seg][ec] = run;
    __syncthreads();

    float off = bias[n * EE + e];
    // seg is wave-uniform -> no divergence
    for (int s = 0; s < seg; ++s) off += part[s][ec];

    if (seg == 0) C[((size_t)n * (KK + 1)) * EE + e] = off;      // row 0 = bias
    float* c = C + ((size_t)(n * (KK + 1) + seg * 32 + 1)) * EE + e;
#pragma unroll
    for (int kk = 0; kk < 32; ++kk)
        c[(size_t)kk * EE] = off + r[kk];
}

// ---- Kernel 2: per (b,n) binary search -> packed {bidx, frac}
__global__ __launch_bounds__(256) void idx_kernel(
        const float* __restrict__ X,
        const float* __restrict__ boundaries,
        int2* __restrict__ pack) {
    int i = blockIdx.x * 256 + threadIdx.x;   // b*N + n (coalesced X read)
    int n = i & (NN - 1);
    float x = X[i];
    const float* bnd = boundaries + n * (KK + 1);
    // lower_bound over inner = bnd[1 .. K-1] (127 elems), result in [0,127]
    int lo = 0, hi = KK - 1;
    while (lo < hi) {
        int mid = (lo + hi) >> 1;
        if (bnd[1 + mid] < x) lo = mid + 1; else hi = mid;
    }
    float s = bnd[lo];
    float en = bnd[lo + 1];
    int2 p;
    p.x = lo;
    p.y = __float_as_int((x - s) / (en - s + EPSF));
    pack[i] = p;
}

// ---- Kernel 3: out[b,n,:] = relu(lerp(C[n,bi,:], C[n,bi+1,:], frac))
// 8 items/block (all same n), 256 thr = 2 groups of 128, float4/thread
// (128*16B = one E-row). n-major item order keeps each XCD's L2 working
// set at one ~258KB C[n] slab. Regular cached stores (m13 ceiling path).
__global__ __launch_bounds__(256) void gather_kernel(
        const float* __restrict__ C,
        const int2* __restrict__ pack,
        float* __restrict__ out) {
    int base = blockIdx.x << 3;              // first of 8 items, same n
    int g    = threadIdx.x >> 7;             // 0..1: item subgroup
    int e    = (threadIdx.x & 127) << 2;     // 0..508 step 4

    int n = base >> 12;                      // t / B (B=4096); uniform in block
    const float* Cn = C + ((size_t)n * (KK + 1)) * EE;  // scalar base

#pragma unroll
    for (int it = 0; it < 4; ++it) {
        int t = base + (g << 2) + it;
        int b = t & (BB - 1);
        int i = b * NN + n;
        int2 p = pack[i];                    // 8B broadcast load
        int   bi = p.x;
        float f  = __int_as_float(p.y);

        const f32x4* c0 = (const f32x4*)(Cn + (size_t)bi * EE + e);
        f32x4 lo = c0[0];
        f32x4 hi = c0[EE / 4];               // +E floats = next j row
        f32x4 r;
        r.x = fmaxf(fmaf(f, hi.x - lo.x, lo.x), 0.f);
        r.y = fmaxf(fmaf(f, hi.y - lo.y, lo.y), 0.f);
        r.z = fmaxf(fmaf(f, hi.z - lo.z, lo.z), 0.f);
        r.w = fmaxf(fmaf(f, hi.w - lo.w, lo.w), 0.f);

        *(f32x4*)(out + ((size_t)b * NN + n) * EE + e) = r;   // cached store
    }
}

extern "C" void kernel_launch(void* const* d_in, const int* in_sizes, int n_in,
                              void* d_out, int out_size, void* d_ws, size_t ws_size,
                              hipStream_t stream) {
    const float* X          = (const float*)d_in[0];
    const float* boundaries = (const float*)d_in[1];
    const float* weight     = (const float*)d_in[2];
    const float* bias       = (const float*)d_in[3];
    float* out = (float*)d_out;

    // ws layout: C table (16.9MB) | pack (2MB)
    float* C = (float*)d_ws;
    size_t Csz = (size_t)NN * (KK + 1) * EE;
    int2* pack = (int2*)(C + Csz);

    cumsum_kernel<<<NN * (EE / 64), 256, 0, stream>>>(weight, bias, C);
    idx_kernel<<<(BB * NN) / 256, 256, 0, stream>>>(X, boundaries, pack);
    gather_kernel<<<(BB * NN) / 8, 256, 0, stream>>>(C, pack, out);
}

// Round 5
// 535.895 us; speedup vs baseline: 1.0584x; 1.0584x over previous
//
#include <hip/hip_runtime.h>

// PiecewiseContEmbeddings: B=4096, N=64, K=128, E=512, fp32.
//
// Identity: boundaries rows are sorted, so the reference's mask is
//   mask[b,n,k] = 1 (k < bidx), frac (k == bidx), 0 (k > bidx).
// Hence out[b,n,:] = relu( lerp(C[n,bidx,:], C[n,bidx+1,:], frac) )
// with C[n,j,:] = bias[n,:] + prefix_sum_{k<j} weight[n,k,:].
//
// R4 post-mortem: cached stores REGRESSED vs nt (567 vs 554) -> keep nt.
// R5 change: gather item order n-major -> b-major. Old order wrote 2KB
// chunks at exact 128KB (2^17) stride -> HBM channel aliasing, ~3TB/s
// effective. New order: block beta handles b=beta>>3, n in [(beta&7)*8,+8)
// -> 16KB contiguous write per block, globally sequential write stream.
// Side effect: XCD round-robin (beta%8 = n-octant) keeps per-XCD C reads
// at 8 slabs = 2.1MB (fits 4MiB L2).

#define BB 4096
#define NN 64
#define KK 128
#define EE 512
#define EPSF 1e-8f

typedef float f32x4 __attribute__((ext_vector_type(4)));

// ---- Kernel 1: C[n,j,e] = bias[n,e] + sum_{k<j} weight[n,k,e], j in [0,K]
// Block-scan: 512 blocks x 256 thr. Block = (n, 64-wide e-chunk).
// tid = seg*64 + ec; seg in [0,4) owns k-range [seg*32, seg*32+32).
__global__ __launch_bounds__(256) void cumsum_kernel(
        const float* __restrict__ weight,
        const float* __restrict__ bias,
        float* __restrict__ C) {
    int n   = blockIdx.x >> 3;          // 64 n values
    int e0  = (blockIdx.x & 7) << 6;    // 8 chunks of 64 e
    int ec  = threadIdx.x & 63;
    int seg = threadIdx.x >> 6;         // wave id == segment id (uniform/wave)
    int e   = e0 + ec;

    const float* w = weight + ((size_t)(n * KK + seg * 32)) * EE + e;
    float r[32];
    float run = 0.f;
#pragma unroll
    for (int kk = 0; kk < 32; ++kk) {
        run += __builtin_nontemporal_load(&w[(size_t)kk * EE]);  // weight read once
        r[kk] = run;
    }

    __shared__ float part[4][64];
    part[seg][ec] = run;
    __syncthreads();

    float off = bias[n * EE + e];
    // seg is wave-uniform -> no divergence
    for (int s = 0; s < seg; ++s) off += part[s][ec];

    if (seg == 0) C[((size_t)n * (KK + 1)) * EE + e] = off;      // row 0 = bias
    float* c = C + ((size_t)(n * (KK + 1) + seg * 32 + 1)) * EE + e;
#pragma unroll
    for (int kk = 0; kk < 32; ++kk)
        c[(size_t)kk * EE] = off + r[kk];
}

// ---- Kernel 2: per (b,n) binary search -> packed {bidx, frac}
__global__ __launch_bounds__(256) void idx_kernel(
        const float* __restrict__ X,
        const float* __restrict__ boundaries,
        int2* __restrict__ pack) {
    int i = blockIdx.x * 256 + threadIdx.x;   // b*N + n (coalesced X read)
    int n = i & (NN - 1);
    float x = X[i];
    const float* bnd = boundaries + n * (KK + 1);
    // lower_bound over inner = bnd[1 .. K-1] (127 elems), result in [0,127]
    int lo = 0, hi = KK - 1;
    while (lo < hi) {
        int mid = (lo + hi) >> 1;
        if (bnd[1 + mid] < x) lo = mid + 1; else hi = mid;
    }
    float s = bnd[lo];
    float en = bnd[lo + 1];
    int2 p;
    p.x = lo;
    p.y = __float_as_int((x - s) / (en - s + EPSF));
    pack[i] = p;
}

// ---- Kernel 3: out[b,n,:] = relu(lerp(C[n,bi,:], C[n,bi+1,:], frac))
// b-major: block beta -> b = beta>>3, 8 consecutive n starting n0=(beta&7)*8.
// 256 thr = 2 groups of 128; group g handles items n0+4g .. n0+4g+3,
// float4/thread (128*16B = one E-row). Writes: 16KB contiguous per block,
// globally sequential. nt stores (R2 vs R4: nt is 13us faster).
__global__ __launch_bounds__(256) void gather_kernel(
        const float* __restrict__ C,
        const int2* __restrict__ pack,
        float* __restrict__ out) {
    int b  = blockIdx.x >> 3;
    int n0 = (blockIdx.x & 7) << 3;          // n-octant (== XCD under %8 rr)
    int g  = threadIdx.x >> 7;               // 0..1: item subgroup (wave-uniform)
    int e  = (threadIdx.x & 127) << 2;       // 0..508 step 4

#pragma unroll
    for (int it = 0; it < 4; ++it) {
        int n = n0 + (g << 2) + it;
        int i = b * NN + n;
        int2 p = pack[i];                    // 8B broadcast load
        int   bi = p.x;
        float f  = __int_as_float(p.y);

        const f32x4* c0 = (const f32x4*)(C + ((size_t)(n * (KK + 1) + bi)) * EE + e);
        f32x4 lo = c0[0];
        f32x4 hi = c0[EE / 4];               // +E floats = next j row
        f32x4 r;
        r.x = fmaxf(fmaf(f, hi.x - lo.x, lo.x), 0.f);
        r.y = fmaxf(fmaf(f, hi.y - lo.y, lo.y), 0.f);
        r.z = fmaxf(fmaf(f, hi.z - lo.z, lo.z), 0.f);
        r.w = fmaxf(fmaf(f, hi.w - lo.w, lo.w), 0.f);

        f32x4* dst = (f32x4*)(out + (size_t)i * EE + e);
        __builtin_nontemporal_store(r, dst);
    }
}

extern "C" void kernel_launch(void* const* d_in, const int* in_sizes, int n_in,
                              void* d_out, int out_size, void* d_ws, size_t ws_size,
                              hipStream_t stream) {
    const float* X          = (const float*)d_in[0];
    const float* boundaries = (const float*)d_in[1];
    const float* weight     = (const float*)d_in[2];
    const float* bias       = (const float*)d_in[3];
    float* out = (float*)d_out;

    // ws layout: C table (16.9MB) | pack (2MB)
    float* C = (float*)d_ws;
    size_t Csz = (size_t)NN * (KK + 1) * EE;
    int2* pack = (int2*)(C + Csz);

    cumsum_kernel<<<NN * (EE / 64), 256, 0, stream>>>(weight, bias, C);
    idx_kernel<<<(BB * NN) / 256, 256, 0, stream>>>(X, boundaries, pack);
    gather_kernel<<<(BB * NN) / 8, 256, 0, stream>>>(C, pack, out);
}